// Round 2
// baseline (780.741 us; speedup 1.0000x reference)
//
#include <hip/hip_runtime.h>
#include <stdint.h>

using u16 = unsigned short;
typedef __attribute__((ext_vector_type(8))) short short8;   // 8 bf16 (4 VGPRs) MFMA A/B frag
typedef __attribute__((ext_vector_type(4))) float floatx4;  // MFMA C/D frag

__device__ __forceinline__ float b2f(u16 s) {
    union { unsigned u; float f; } x; x.u = ((unsigned)s) << 16; return x.f;
}
__device__ __forceinline__ u16 f2b(float f) {
    unsigned u = __float_as_uint(f);
    unsigned r = (u + 0x7fffu + ((u >> 16) & 1u)) >> 16;  // RNE
    return (u16)r;
}

// ---------------------------------------------------------------------------
// GroupNorm stats: one block per (b,g); mean/var over H*W*(C/G) = 65536 f32
// ---------------------------------------------------------------------------
__global__ __launch_bounds__(256) void gn_stats_k(const float* __restrict__ x,
                                                  float* __restrict__ stats) {
    int bg = blockIdx.x;               // 0..127
    int b = bg >> 5, g = bg & 31;
    const size_t base = (size_t)b * 4096 * 512 + g * 16;
    int t = threadIdx.x;
    float s = 0.f, ss = 0.f;
    for (int it = 0; it < 64; ++it) {
        int vi = it * 256 + t;         // 16384 float4 vectors
        int n = vi >> 2;               // token 0..4095
        int j = (vi & 3) * 4;          // channel-within-group 0,4,8,12
        float4 u = *(const float4*)(x + base + (size_t)n * 512 + j);
        s += u.x + u.y + u.z + u.w;
        ss += u.x * u.x + u.y * u.y + u.z * u.z + u.w * u.w;
    }
    for (int off = 32; off; off >>= 1) {
        s  += __shfl_down(s, off, 64);
        ss += __shfl_down(ss, off, 64);
    }
    __shared__ float rs[4], rss[4];
    int lane = t & 63, w = t >> 6;
    if (lane == 0) { rs[w] = s; rss[w] = ss; }
    __syncthreads();
    if (t == 0) {
        float S1 = rs[0] + rs[1] + rs[2] + rs[3];
        float S2 = rss[0] + rss[1] + rss[2] + rss[3];
        float mean = S1 * (1.f / 65536.f);
        float var  = S2 * (1.f / 65536.f) - mean * mean;
        stats[2 * bg]     = mean;
        stats[2 * bg + 1] = rsqrtf(var + 1e-6f);
    }
}

// ---------------------------------------------------------------------------
// GroupNorm apply: h(bf16) = (x - mean) * rstd * gamma + beta, 4 f32/thread
// ---------------------------------------------------------------------------
__global__ __launch_bounds__(256) void gn_apply_k(const float* __restrict__ x,
                                                  const float* __restrict__ gamma,
                                                  const float* __restrict__ beta,
                                                  const float* __restrict__ stats,
                                                  u16* __restrict__ h) {
    size_t v = (size_t)blockIdx.x * 256 + threadIdx.x;   // float4 index
    size_t e = v * 4;
    int c = (int)(e & 511);            // multiple of 4; never crosses 16-ch group
    int b = (int)(e >> 21);            // e / (4096*512)
    int g = c >> 4;
    float mean = stats[2 * (b * 32 + g)];
    float rstd = stats[2 * (b * 32 + g) + 1];
    float4 xv = *(const float4*)(x + e);
    float4 gv = *(const float4*)(gamma + c);
    float4 bv = *(const float4*)(beta + c);
    ushort4 o;
    o.x = f2b((xv.x - mean) * rstd * gv.x + bv.x);
    o.y = f2b((xv.y - mean) * rstd * gv.y + bv.y);
    o.z = f2b((xv.z - mean) * rstd * gv.z + bv.z);
    o.w = f2b((xv.w - mean) * rstd * gv.w + bv.w);
    *(ushort4*)(h + e) = o;
}

// ---------------------------------------------------------------------------
// 512x512 fp32 -> bf16 transposed copy (for weight matrices)
// ---------------------------------------------------------------------------
__global__ __launch_bounds__(256) void transpose_f2b(const float* __restrict__ src,
                                                     u16* __restrict__ dst) {
    __shared__ float tile[32][33];
    int tx = threadIdx.x, ty = threadIdx.y;   // (32,8)
    int r0 = blockIdx.x * 32, c0 = blockIdx.y * 32;
#pragma unroll
    for (int i = 0; i < 4; ++i)
        tile[ty + i * 8][tx] = src[(size_t)(r0 + ty + i * 8) * 512 + c0 + tx];
    __syncthreads();
#pragma unroll
    for (int i = 0; i < 4; ++i)
        dst[(size_t)(c0 + ty + i * 8) * 512 + r0 + tx] = f2b(tile[tx][ty + i * 8]);
}

// ---------------------------------------------------------------------------
// bf16 -> bf16 transposed copy (V tiles), batched via blockIdx.z
// ---------------------------------------------------------------------------
__global__ __launch_bounds__(256) void transpose_b2b(const u16* __restrict__ src,
                                                     u16* __restrict__ dst,
                                                     int src_ld, int dst_ld,
                                                     long long sSrc, long long sDst) {
    __shared__ u16 tile[32][33];
    src += (size_t)blockIdx.z * sSrc;
    dst += (size_t)blockIdx.z * sDst;
    int tx = threadIdx.x, ty = threadIdx.y;   // (32,8)
    int r0 = blockIdx.x * 32, c0 = blockIdx.y * 32;
#pragma unroll
    for (int i = 0; i < 4; ++i)
        tile[ty + i * 8][tx] = src[(size_t)(r0 + ty + i * 8) * src_ld + c0 + tx];
    __syncthreads();
#pragma unroll
    for (int i = 0; i < 4; ++i)
        dst[(size_t)(c0 + ty + i * 8) * dst_ld + r0 + tx] = tile[tx][ty + i * 8];
}

__global__ __launch_bounds__(256) void concat_bias_f(const float* __restrict__ bq,
                                                     const float* __restrict__ bk,
                                                     const float* __restrict__ bv,
                                                     float* __restrict__ dst) {
    int i = blockIdx.x * 256 + threadIdx.x;   // 1536
    const float* src = (i < 512) ? bq : (i < 1024) ? bk : bv;
    dst[i] = src[i & 511];
}

// ---------------------------------------------------------------------------
// GEMM, C = scale*(A @ B^T) + bias (+resid), bf16 operands, fp32 accum.
// Output bf16 to C (if Cf==null) else fp32 to Cf. 128x128 tile, 4 waves,
// each wave 64x64 via 4x4 of 16x16x32 bf16 MFMA. M,N%128==0, K%32==0.
// ---------------------------------------------------------------------------
__global__ __launch_bounds__(256) void gemm_bt(const u16* __restrict__ A, int lda,
                                               const u16* __restrict__ B, int ldb,
                                               u16* __restrict__ C, float* __restrict__ Cf,
                                               int ldc,
                                               const float* __restrict__ bias,
                                               const float* __restrict__ resid,
                                               int K, float scale) {
    __shared__ u16 As[128 * 32];
    __shared__ u16 Bs[128 * 32];
    const int t = threadIdx.x;
    const int lane = t & 63, w = t >> 6;
    const int wm = (w >> 1) * 64, wn = (w & 1) * 64;
    const int r = lane & 15, q = lane >> 4;
    const int m0 = blockIdx.x * 128;
    const int n0 = blockIdx.y * 128;

    floatx4 acc[4][4];
#pragma unroll
    for (int mi = 0; mi < 4; ++mi)
#pragma unroll
        for (int ni = 0; ni < 4; ++ni) acc[mi][ni] = (floatx4){0.f, 0.f, 0.f, 0.f};

    const int arow = t >> 2;            // 0..63
    const int akc  = (t & 3) * 8;       // 0,8,16,24

    for (int k0 = 0; k0 < K; k0 += 32) {
        uint4 a0 = *(const uint4*)(A + (size_t)(m0 + arow) * lda + k0 + akc);
        uint4 a1 = *(const uint4*)(A + (size_t)(m0 + 64 + arow) * lda + k0 + akc);
        uint4 b0 = *(const uint4*)(B + (size_t)(n0 + arow) * ldb + k0 + akc);
        uint4 b1 = *(const uint4*)(B + (size_t)(n0 + 64 + arow) * ldb + k0 + akc);
        __syncthreads();   // previous iter's LDS reads complete
        *(uint4*)(As + arow * 32 + akc)        = a0;
        *(uint4*)(As + (64 + arow) * 32 + akc) = a1;
        *(uint4*)(Bs + arow * 32 + akc)        = b0;
        *(uint4*)(Bs + (64 + arow) * 32 + akc) = b1;
        __syncthreads();
        short8 af[4], bfr[4];
#pragma unroll
        for (int mi = 0; mi < 4; ++mi)
            af[mi] = *(const short8*)(As + (wm + mi * 16 + r) * 32 + q * 8);
#pragma unroll
        for (int ni = 0; ni < 4; ++ni)
            bfr[ni] = *(const short8*)(Bs + (wn + ni * 16 + r) * 32 + q * 8);
#pragma unroll
        for (int mi = 0; mi < 4; ++mi)
#pragma unroll
            for (int ni = 0; ni < 4; ++ni)
                acc[mi][ni] = __builtin_amdgcn_mfma_f32_16x16x32_bf16(af[mi], bfr[ni],
                                                                      acc[mi][ni], 0, 0, 0);
    }

#pragma unroll
    for (int ni = 0; ni < 4; ++ni) {
        int col = n0 + wn + ni * 16 + r;
        float bv = bias ? bias[col] : 0.f;
#pragma unroll
        for (int mi = 0; mi < 4; ++mi) {
            int rowb = m0 + wm + mi * 16 + q * 4;
#pragma unroll
            for (int i = 0; i < 4; ++i) {
                size_t off = (size_t)(rowb + i) * ldc + col;
                float v = acc[mi][ni][i] * scale + bv;
                if (resid) v += resid[off];
                if (Cf) Cf[off] = v;
                else    C[off] = f2b(v);
            }
        }
    }
}

// ---------------------------------------------------------------------------
// Row softmax in-place on bf16 scores, one block per row of 4096
// ---------------------------------------------------------------------------
__global__ __launch_bounds__(256) void softmax_k(u16* __restrict__ S) {
    size_t row = blockIdx.x;
    u16* p = S + row * 4096;
    int t = threadIdx.x;
    uint4 u0 = *(const uint4*)(p + t * 16);
    uint4 u1 = *(const uint4*)(p + t * 16 + 8);
    const u16* a0 = (const u16*)&u0;
    const u16* a1 = (const u16*)&u1;
    float vals[16];
#pragma unroll
    for (int j = 0; j < 8; ++j) { vals[j] = b2f(a0[j]); vals[8 + j] = b2f(a1[j]); }
    float m = -1e30f;
#pragma unroll
    for (int j = 0; j < 16; ++j) m = fmaxf(m, vals[j]);
    for (int off = 32; off; off >>= 1) m = fmaxf(m, __shfl_down(m, off, 64));
    __shared__ float red[4];
    __shared__ float bc;
    int lane = t & 63, w = t >> 6;
    if (lane == 0) red[w] = m;
    __syncthreads();
    if (t == 0) bc = fmaxf(fmaxf(red[0], red[1]), fmaxf(red[2], red[3]));
    __syncthreads();
    m = bc;
    float s = 0.f;
#pragma unroll
    for (int j = 0; j < 16; ++j) { vals[j] = __expf(vals[j] - m); s += vals[j]; }
    for (int off = 32; off; off >>= 1) s += __shfl_down(s, off, 64);
    __syncthreads();                 // bc/red reads above done before overwrite
    if (lane == 0) red[w] = s;
    __syncthreads();
    if (t == 0) bc = red[0] + red[1] + red[2] + red[3];
    __syncthreads();
    float inv = 1.f / bc;
    uint4 o0, o1; u16* w0 = (u16*)&o0; u16* w1 = (u16*)&o1;
#pragma unroll
    for (int j = 0; j < 8; ++j) { w0[j] = f2b(vals[j] * inv); w1[j] = f2b(vals[8 + j] * inv); }
    *(uint4*)(p + t * 16)     = o0;
    *(uint4*)(p + t * 16 + 8) = o1;
}

// ---------------------------------------------------------------------------
extern "C" void kernel_launch(void* const* d_in, const int* in_sizes, int n_in,
                              void* d_out, int out_size, void* d_ws, size_t ws_size,
                              hipStream_t stream) {
    const float* x     = (const float*)d_in[0];
    const float* gamma = (const float*)d_in[1];
    const float* beta  = (const float*)d_in[2];
    const float* Wq    = (const float*)d_in[3];
    const float* bq    = (const float*)d_in[4];
    const float* Wk    = (const float*)d_in[5];
    const float* bk    = (const float*)d_in[6];
    const float* Wv    = (const float*)d_in[7];
    const float* bv    = (const float*)d_in[8];
    const float* Wo    = (const float*)d_in[9];
    const float* bo    = (const float*)d_in[10];
    float* out = (float*)d_out;

    // B=4, N=4096 tokens, C=512, G=32 — ws layout (bytes), total ~114 MiB
    char* ws = (char*)d_ws;
    float* stats  = (float*)(ws);                        // 128*2 f32   @ 0
    float* bqkv   = (float*)(ws + 4096);                 // 1536 f32    @ 4096
    u16*   wqkv_t = (u16*)(ws + 16384);                  // [1536,512]  @ 16384
    u16*   wo_t   = wqkv_t + (size_t)1536 * 512;
    u16*   h      = wo_t + (size_t)512 * 512;            // [16384,512] (aliased as ao later)
    u16*   qkv    = h   + (size_t)16384 * 512;           // [16384,1536]
    u16*   vt     = qkv + (size_t)16384 * 1536;          // [4][512][4096]
    u16*   S      = vt  + (size_t)16384 * 512;           // [4096,4096] (reused per batch)
    u16*   ao     = h;                                   // h is dead after QKV GEMM

    dim3 tblk(32, 8, 1);
    // Weight transposes (fp32 -> bf16, B^T [N,K] form)
    transpose_f2b<<<dim3(16, 16, 1), tblk, 0, stream>>>(Wq, wqkv_t);
    transpose_f2b<<<dim3(16, 16, 1), tblk, 0, stream>>>(Wk, wqkv_t + 512 * 512);
    transpose_f2b<<<dim3(16, 16, 1), tblk, 0, stream>>>(Wv, wqkv_t + 1024 * 512);
    transpose_f2b<<<dim3(16, 16, 1), tblk, 0, stream>>>(Wo, wo_t);
    concat_bias_f<<<6, 256, 0, stream>>>(bq, bk, bv, bqkv);

    gn_stats_k<<<128, 256, 0, stream>>>(x, stats);
    gn_apply_k<<<8192, 256, 0, stream>>>(x, gamma, beta, stats, h);

    // QKV: [16384,512] @ [512,1536] -> qkv (+bias)
    gemm_bt<<<dim3(128, 12, 1), 256, 0, stream>>>(h, 512, wqkv_t, 512,
                                                  qkv, nullptr, 1536, bqkv, nullptr,
                                                  512, 1.0f);
    // v -> vt[b][c][n]
    transpose_b2b<<<dim3(128, 16, 4), tblk, 0, stream>>>(qkv + 1024, vt, 1536, 4096,
                                                         (long long)4096 * 1536,
                                                         (long long)512 * 4096);
    // Per-batch attention (stream-ordered reuse of S)
    for (int b = 0; b < 4; ++b) {
        const u16* qb = qkv + (size_t)b * 4096 * 1536;
        const u16* kb = qb + 512;
        const u16* vb = vt + (size_t)b * 512 * 4096;
        u16* aob = ao + (size_t)b * 4096 * 512;
        // scores = q @ k^T / sqrt(C)
        gemm_bt<<<dim3(32, 32, 1), 256, 0, stream>>>(qb, 1536, kb, 1536,
                                                     S, nullptr, 4096, nullptr, nullptr,
                                                     512, 0.04419417382415922f);
        softmax_k<<<4096, 256, 0, stream>>>(S);
        // ao = P @ v   (vt is [c][n] per batch -> B^T form)
        gemm_bt<<<dim3(32, 4, 1), 256, 0, stream>>>(S, 4096, vb, 4096,
                                                    aob, nullptr, 512, nullptr, nullptr,
                                                    4096, 1.0f);
    }
    // out = ao @ Wo + bo + x   (fp32 output + fp32 bias + fp32 residual)
    gemm_bt<<<dim3(128, 4, 1), 256, 0, stream>>>(ao, 512, wo_t, 512,
                                                 nullptr, out, 512, bo, x,
                                                 512, 1.0f);
}

// Round 3
// 544.272 us; speedup vs baseline: 1.4345x; 1.4345x over previous
//
#include <hip/hip_runtime.h>
#include <stdint.h>

using u16 = unsigned short;
typedef __attribute__((ext_vector_type(8))) short short8;   // 8 bf16 (4 VGPRs) MFMA A/B frag
typedef __attribute__((ext_vector_type(4))) float floatx4;  // MFMA C/D frag

__device__ __forceinline__ float b2f(u16 s) {
    union { unsigned u; float f; } x; x.u = ((unsigned)s) << 16; return x.f;
}
__device__ __forceinline__ u16 f2b(float f) {
    unsigned u = __float_as_uint(f);
    unsigned r = (u + 0x7fffu + ((u >> 16) & 1u)) >> 16;  // RNE
    return (u16)r;
}

// async global->LDS, 16B per lane; lds dst = wave-uniform base + lane*16
__device__ __forceinline__ void gl16(const u16* g, u16* l) {
    __builtin_amdgcn_global_load_lds((const __attribute__((address_space(1))) void*)g,
                                     (__attribute__((address_space(3))) void*)l,
                                     16, 0, 0);
}

// ---------------------------------------------------------------------------
// GroupNorm stats: one block per (b,g); mean/var over H*W*(C/G) = 65536 f32
// ---------------------------------------------------------------------------
__global__ __launch_bounds__(256) void gn_stats_k(const float* __restrict__ x,
                                                  float* __restrict__ stats) {
    int bg = blockIdx.x;               // 0..127
    int b = bg >> 5, g = bg & 31;
    const size_t base = (size_t)b * 4096 * 512 + g * 16;
    int t = threadIdx.x;
    float s = 0.f, ss = 0.f;
    for (int it = 0; it < 64; ++it) {
        int vi = it * 256 + t;         // 16384 float4 vectors
        int n = vi >> 2;               // token 0..4095
        int j = (vi & 3) * 4;          // channel-within-group 0,4,8,12
        float4 u = *(const float4*)(x + base + (size_t)n * 512 + j);
        s += u.x + u.y + u.z + u.w;
        ss += u.x * u.x + u.y * u.y + u.z * u.z + u.w * u.w;
    }
    for (int off = 32; off; off >>= 1) {
        s  += __shfl_down(s, off, 64);
        ss += __shfl_down(ss, off, 64);
    }
    __shared__ float rs[4], rss[4];
    int lane = t & 63, w = t >> 6;
    if (lane == 0) { rs[w] = s; rss[w] = ss; }
    __syncthreads();
    if (t == 0) {
        float S1 = rs[0] + rs[1] + rs[2] + rs[3];
        float S2 = rss[0] + rss[1] + rss[2] + rss[3];
        float mean = S1 * (1.f / 65536.f);
        float var  = S2 * (1.f / 65536.f) - mean * mean;
        stats[2 * bg]     = mean;
        stats[2 * bg + 1] = rsqrtf(var + 1e-6f);
    }
}

// ---------------------------------------------------------------------------
// GroupNorm apply: h(bf16) = (x - mean) * rstd * gamma + beta, 4 f32/thread
// ---------------------------------------------------------------------------
__global__ __launch_bounds__(256) void gn_apply_k(const float* __restrict__ x,
                                                  const float* __restrict__ gamma,
                                                  const float* __restrict__ beta,
                                                  const float* __restrict__ stats,
                                                  u16* __restrict__ h) {
    size_t v = (size_t)blockIdx.x * 256 + threadIdx.x;   // float4 index
    size_t e = v * 4;
    int c = (int)(e & 511);            // multiple of 4; never crosses 16-ch group
    int b = (int)(e >> 21);            // e / (4096*512)
    int g = c >> 4;
    float mean = stats[2 * (b * 32 + g)];
    float rstd = stats[2 * (b * 32 + g) + 1];
    float4 xv = *(const float4*)(x + e);
    float4 gv = *(const float4*)(gamma + c);
    float4 bv = *(const float4*)(beta + c);
    ushort4 o;
    o.x = f2b((xv.x - mean) * rstd * gv.x + bv.x);
    o.y = f2b((xv.y - mean) * rstd * gv.y + bv.y);
    o.z = f2b((xv.z - mean) * rstd * gv.z + bv.z);
    o.w = f2b((xv.w - mean) * rstd * gv.w + bv.w);
    *(ushort4*)(h + e) = o;
}

// ---------------------------------------------------------------------------
// 512x512 fp32 -> bf16 transposed copy (for weight matrices)
// ---------------------------------------------------------------------------
__global__ __launch_bounds__(256) void transpose_f2b(const float* __restrict__ src,
                                                     u16* __restrict__ dst) {
    __shared__ float tile[32][33];
    int tx = threadIdx.x, ty = threadIdx.y;   // (32,8)
    int r0 = blockIdx.x * 32, c0 = blockIdx.y * 32;
#pragma unroll
    for (int i = 0; i < 4; ++i)
        tile[ty + i * 8][tx] = src[(size_t)(r0 + ty + i * 8) * 512 + c0 + tx];
    __syncthreads();
#pragma unroll
    for (int i = 0; i < 4; ++i)
        dst[(size_t)(c0 + ty + i * 8) * 512 + r0 + tx] = f2b(tile[tx][ty + i * 8]);
}

// ---------------------------------------------------------------------------
// bf16 -> bf16 transposed copy (V tiles), batched via blockIdx.z
// ---------------------------------------------------------------------------
__global__ __launch_bounds__(256) void transpose_b2b(const u16* __restrict__ src,
                                                     u16* __restrict__ dst,
                                                     int src_ld, int dst_ld,
                                                     long long sSrc, long long sDst) {
    __shared__ u16 tile[32][33];
    src += (size_t)blockIdx.z * sSrc;
    dst += (size_t)blockIdx.z * sDst;
    int tx = threadIdx.x, ty = threadIdx.y;   // (32,8)
    int r0 = blockIdx.x * 32, c0 = blockIdx.y * 32;
#pragma unroll
    for (int i = 0; i < 4; ++i)
        tile[ty + i * 8][tx] = src[(size_t)(r0 + ty + i * 8) * src_ld + c0 + tx];
    __syncthreads();
#pragma unroll
    for (int i = 0; i < 4; ++i)
        dst[(size_t)(c0 + ty + i * 8) * dst_ld + r0 + tx] = tile[tx][ty + i * 8];
}

__global__ __launch_bounds__(256) void concat_bias_f(const float* __restrict__ bq,
                                                     const float* __restrict__ bk,
                                                     const float* __restrict__ bv,
                                                     float* __restrict__ dst) {
    int i = blockIdx.x * 256 + threadIdx.x;   // 1536
    const float* src = (i < 512) ? bq : (i < 1024) ? bk : bv;
    dst[i] = src[i & 511];
}

// ---------------------------------------------------------------------------
// GEMM, C = scale*(A @ B^T) + bias (+resid), bf16 operands, fp32 accum,
// batched via blockIdx.z with element strides sA/sB/sC.
// global_load_lds(16B) staging (m97 pattern). Output bf16 to C or fp32 to Cf.
// 128x128 tile, 4 waves, each wave 64x64 via 4x4 of 16x16x32 bf16 MFMA.
// M,N%128==0, K%32==0, lda/ldb even (16B-aligned rows).
// ---------------------------------------------------------------------------
__global__ __launch_bounds__(256) void gemm_bt(const u16* __restrict__ A, int lda, long long sA,
                                               const u16* __restrict__ B, int ldb, long long sB,
                                               u16* __restrict__ C, float* __restrict__ Cf,
                                               int ldc, long long sC,
                                               const float* __restrict__ bias,
                                               const float* __restrict__ resid,
                                               int K, float scale) {
    __shared__ u16 As[128 * 32];
    __shared__ u16 Bs[128 * 32];
    const int t = threadIdx.x;
    const int lane = t & 63, w = t >> 6;
    const int wm = (w >> 1) * 64, wn = (w & 1) * 64;
    const int r = lane & 15, q = lane >> 4;
    const size_t z = blockIdx.z;
    A += z * sA; B += z * sB;
    if (Cf) Cf += z * sC; else C += z * sC;
    const int m0 = blockIdx.x * 128;
    const int n0 = blockIdx.y * 128;

    floatx4 acc[4][4];
#pragma unroll
    for (int mi = 0; mi < 4; ++mi)
#pragma unroll
        for (int ni = 0; ni < 4; ++ni) acc[mi][ni] = (floatx4){0.f, 0.f, 0.f, 0.f};

    // staging: wave w covers rows w*32..w*32+31 (two 16-row instrs/lane);
    // LDS dst = wave-uniform base + lane*16B  ->  elem (w*32+j*16+lane/4)*32 + (lane&3)*8
    const int srow = lane >> 2;
    const int scol = (lane & 3) * 8;
    const u16* gA = A + (size_t)(m0 + w * 32 + srow) * lda + scol;
    const u16* gB = B + (size_t)(n0 + w * 32 + srow) * ldb + scol;
    u16* lA = As + w * 1024;
    u16* lB = Bs + w * 1024;

    for (int k0 = 0; k0 < K; k0 += 32) {
        __syncthreads();   // previous iter's LDS reads complete
        gl16(gA,                     lA);
        gl16(gA + (size_t)16 * lda,  lA + 512);
        gl16(gB,                     lB);
        gl16(gB + (size_t)16 * ldb,  lB + 512);
        gA += 32; gB += 32;
        __syncthreads();   // staging (vmcnt) drained
        short8 af[4], bfr[4];
#pragma unroll
        for (int mi = 0; mi < 4; ++mi)
            af[mi] = *(const short8*)(As + (wm + mi * 16 + r) * 32 + q * 8);
#pragma unroll
        for (int ni = 0; ni < 4; ++ni)
            bfr[ni] = *(const short8*)(Bs + (wn + ni * 16 + r) * 32 + q * 8);
#pragma unroll
        for (int mi = 0; mi < 4; ++mi)
#pragma unroll
            for (int ni = 0; ni < 4; ++ni)
                acc[mi][ni] = __builtin_amdgcn_mfma_f32_16x16x32_bf16(af[mi], bfr[ni],
                                                                      acc[mi][ni], 0, 0, 0);
    }

#pragma unroll
    for (int ni = 0; ni < 4; ++ni) {
        int col = n0 + wn + ni * 16 + r;
        float bv = bias ? bias[col] : 0.f;
#pragma unroll
        for (int mi = 0; mi < 4; ++mi) {
            int rowb = m0 + wm + mi * 16 + q * 4;
#pragma unroll
            for (int i = 0; i < 4; ++i) {
                size_t off = (size_t)(rowb + i) * ldc + col;
                float v = acc[mi][ni][i] * scale + bv;
                if (resid) v += resid[off];
                if (Cf) Cf[off] = v;
                else    C[off] = f2b(v);
            }
        }
    }
}

// ---------------------------------------------------------------------------
// Row softmax in-place on bf16 scores; row = blockIdx.y*4096 + blockIdx.x
// ---------------------------------------------------------------------------
__global__ __launch_bounds__(256) void softmax_k(u16* __restrict__ S) {
    size_t row = (size_t)blockIdx.y * 4096 + blockIdx.x;
    u16* p = S + row * 4096;
    int t = threadIdx.x;
    uint4 u0 = *(const uint4*)(p + t * 16);
    uint4 u1 = *(const uint4*)(p + t * 16 + 8);
    const u16* a0 = (const u16*)&u0;
    const u16* a1 = (const u16*)&u1;
    float vals[16];
#pragma unroll
    for (int j = 0; j < 8; ++j) { vals[j] = b2f(a0[j]); vals[8 + j] = b2f(a1[j]); }
    float m = -1e30f;
#pragma unroll
    for (int j = 0; j < 16; ++j) m = fmaxf(m, vals[j]);
    for (int off = 32; off; off >>= 1) m = fmaxf(m, __shfl_down(m, off, 64));
    __shared__ float red[4];
    __shared__ float bc;
    int lane = t & 63, w = t >> 6;
    if (lane == 0) red[w] = m;
    __syncthreads();
    if (t == 0) bc = fmaxf(fmaxf(red[0], red[1]), fmaxf(red[2], red[3]));
    __syncthreads();
    m = bc;
    float s = 0.f;
#pragma unroll
    for (int j = 0; j < 16; ++j) { vals[j] = __expf(vals[j] - m); s += vals[j]; }
    for (int off = 32; off; off >>= 1) s += __shfl_down(s, off, 64);
    __syncthreads();                 // bc/red reads above done before overwrite
    if (lane == 0) red[w] = s;
    __syncthreads();
    if (t == 0) bc = red[0] + red[1] + red[2] + red[3];
    __syncthreads();
    float inv = 1.f / bc;
    uint4 o0, o1; u16* w0 = (u16*)&o0; u16* w1 = (u16*)&o1;
#pragma unroll
    for (int j = 0; j < 8; ++j) { w0[j] = f2b(vals[j] * inv); w1[j] = f2b(vals[8 + j] * inv); }
    *(uint4*)(p + t * 16)     = o0;
    *(uint4*)(p + t * 16 + 8) = o1;
}

// ---------------------------------------------------------------------------
extern "C" void kernel_launch(void* const* d_in, const int* in_sizes, int n_in,
                              void* d_out, int out_size, void* d_ws, size_t ws_size,
                              hipStream_t stream) {
    const float* x     = (const float*)d_in[0];
    const float* gamma = (const float*)d_in[1];
    const float* beta  = (const float*)d_in[2];
    const float* Wq    = (const float*)d_in[3];
    const float* bq    = (const float*)d_in[4];
    const float* Wk    = (const float*)d_in[5];
    const float* bk    = (const float*)d_in[6];
    const float* Wv    = (const float*)d_in[7];
    const float* bv    = (const float*)d_in[8];
    const float* Wo    = (const float*)d_in[9];
    const float* bo    = (const float*)d_in[10];
    float* out = (float*)d_out;

    // B=4, N=4096, C=512, G=32 — ws layout
    char* ws = (char*)d_ws;
    float* stats  = (float*)(ws);                        // 128*2 f32
    float* bqkv   = (float*)(ws + 4096);                 // 1536 f32
    u16*   wqkv_t = (u16*)(ws + 16384);                  // [1536,512]
    u16*   wo_t   = wqkv_t + (size_t)1536 * 512;
    u16*   h      = wo_t + (size_t)512 * 512;            // [16384,512] (aliased as ao)
    u16*   qkv    = h   + (size_t)16384 * 512;           // [16384,1536]
    u16*   vt     = qkv + (size_t)16384 * 1536;          // [4][512][4096]
    u16*   S      = vt  + (size_t)16384 * 512;           // 1 or 4 batches of [4096,4096]
    u16*   ao     = h;                                   // h dead after QKV GEMM

    const size_t S_elems = (size_t)4096 * 4096;
    const size_t base_bytes = (size_t)((char*)S - ws);
    const bool batched = ws_size >= base_bytes + 4 * S_elems * sizeof(u16);

    const long long sQKV = (long long)4096 * 1536;
    const long long sVT  = (long long)512 * 4096;
    const long long sAO  = (long long)4096 * 512;
    const float sc = 0.04419417382415922f;   // 512^-0.5

    dim3 tblk(32, 8, 1);
    transpose_f2b<<<dim3(16, 16, 1), tblk, 0, stream>>>(Wq, wqkv_t);
    transpose_f2b<<<dim3(16, 16, 1), tblk, 0, stream>>>(Wk, wqkv_t + 512 * 512);
    transpose_f2b<<<dim3(16, 16, 1), tblk, 0, stream>>>(Wv, wqkv_t + 1024 * 512);
    transpose_f2b<<<dim3(16, 16, 1), tblk, 0, stream>>>(Wo, wo_t);
    concat_bias_f<<<6, 256, 0, stream>>>(bq, bk, bv, bqkv);

    gn_stats_k<<<128, 256, 0, stream>>>(x, stats);
    gn_apply_k<<<8192, 256, 0, stream>>>(x, gamma, beta, stats, h);

    // QKV: [16384,512] @ [512,1536] -> qkv (+bias)
    gemm_bt<<<dim3(128, 12, 1), 256, 0, stream>>>(h, 512, 0, wqkv_t, 512, 0,
                                                  qkv, nullptr, 1536, 0, bqkv, nullptr,
                                                  512, 1.0f);
    // v -> vt[b][c][n]
    transpose_b2b<<<dim3(128, 16, 4), tblk, 0, stream>>>(qkv + 1024, vt, 1536, 4096,
                                                         sQKV, sVT);
    if (batched) {
        // scores[b] = q @ k^T * sc    (4096 blocks)
        gemm_bt<<<dim3(32, 32, 4), 256, 0, stream>>>(qkv, 1536, sQKV, qkv + 512, 1536, sQKV,
                                                     S, nullptr, 4096, (long long)S_elems,
                                                     nullptr, nullptr, 512, sc);
        softmax_k<<<dim3(4096, 4, 1), 256, 0, stream>>>(S);
        // ao[b] = P @ v               (512 blocks)
        gemm_bt<<<dim3(32, 4, 4), 256, 0, stream>>>(S, 4096, (long long)S_elems,
                                                    vt, 4096, sVT,
                                                    ao, nullptr, 512, sAO,
                                                    nullptr, nullptr, 4096, 1.0f);
    } else {
        for (int b = 0; b < 4; ++b) {
            const u16* qb = qkv + (size_t)b * sQKV;
            const u16* vb = vt + (size_t)b * sVT;
            u16* aob = ao + (size_t)b * sAO;
            gemm_bt<<<dim3(32, 32, 1), 256, 0, stream>>>(qb, 1536, 0, qb + 512, 1536, 0,
                                                         S, nullptr, 4096, 0,
                                                         nullptr, nullptr, 512, sc);
            softmax_k<<<dim3(4096, 1, 1), 256, 0, stream>>>(S);
            gemm_bt<<<dim3(32, 4, 1), 256, 0, stream>>>(S, 4096, 0, vb, 4096, 0,
                                                        aob, nullptr, 512, 0,
                                                        nullptr, nullptr, 4096, 1.0f);
        }
    }
    // out = ao @ Wo + bo + x   (fp32 output + bias + residual)
    gemm_bt<<<dim3(128, 4, 1), 256, 0, stream>>>(ao, 512, 0, wo_t, 512, 0,
                                                 nullptr, out, 512, 0, bo, x,
                                                 512, 1.0f);
}

// Round 4
// 513.672 us; speedup vs baseline: 1.5199x; 1.0596x over previous
//
#include <hip/hip_runtime.h>
#include <stdint.h>

using u16 = unsigned short;
typedef __attribute__((ext_vector_type(8))) short short8;   // 8 bf16 (4 VGPRs) MFMA A/B frag
typedef __attribute__((ext_vector_type(4))) float floatx4;  // MFMA C/D frag

__device__ __forceinline__ float b2f(u16 s) {
    union { unsigned u; float f; } x; x.u = ((unsigned)s) << 16; return x.f;
}
__device__ __forceinline__ u16 f2b(float f) {
    unsigned u = __float_as_uint(f);
    unsigned r = (u + 0x7fffu + ((u >> 16) & 1u)) >> 16;  // RNE
    return (u16)r;
}

// async global->LDS, 16B per lane; lds dst = wave-uniform base + lane*16
__device__ __forceinline__ void gl16(const u16* g, u16* l) {
    __builtin_amdgcn_global_load_lds((const __attribute__((address_space(1))) void*)g,
                                     (__attribute__((address_space(3))) void*)l,
                                     16, 0, 0);
}

// ---------------------------------------------------------------------------
// GroupNorm stats: one block per (b,g); mean/var over H*W*(C/G) = 65536 f32
// ---------------------------------------------------------------------------
__global__ __launch_bounds__(256) void gn_stats_k(const float* __restrict__ x,
                                                  float* __restrict__ stats) {
    int bg = blockIdx.x;               // 0..127
    int b = bg >> 5, g = bg & 31;
    const size_t base = (size_t)b * 4096 * 512 + g * 16;
    int t = threadIdx.x;
    float s = 0.f, ss = 0.f;
    for (int it = 0; it < 64; ++it) {
        int vi = it * 256 + t;         // 16384 float4 vectors
        int n = vi >> 2;               // token 0..4095
        int j = (vi & 3) * 4;          // channel-within-group 0,4,8,12
        float4 u = *(const float4*)(x + base + (size_t)n * 512 + j);
        s += u.x + u.y + u.z + u.w;
        ss += u.x * u.x + u.y * u.y + u.z * u.z + u.w * u.w;
    }
    for (int off = 32; off; off >>= 1) {
        s  += __shfl_down(s, off, 64);
        ss += __shfl_down(ss, off, 64);
    }
    __shared__ float rs[4], rss[4];
    int lane = t & 63, w = t >> 6;
    if (lane == 0) { rs[w] = s; rss[w] = ss; }
    __syncthreads();
    if (t == 0) {
        float S1 = rs[0] + rs[1] + rs[2] + rs[3];
        float S2 = rss[0] + rss[1] + rss[2] + rss[3];
        float mean = S1 * (1.f / 65536.f);
        float var  = S2 * (1.f / 65536.f) - mean * mean;
        stats[2 * bg]     = mean;
        stats[2 * bg + 1] = rsqrtf(var + 1e-6f);
    }
}

// ---------------------------------------------------------------------------
// GroupNorm apply: h(bf16) = (x - mean) * rstd * gamma + beta, 4 f32/thread
// ---------------------------------------------------------------------------
__global__ __launch_bounds__(256) void gn_apply_k(const float* __restrict__ x,
                                                  const float* __restrict__ gamma,
                                                  const float* __restrict__ beta,
                                                  const float* __restrict__ stats,
                                                  u16* __restrict__ h) {
    size_t v = (size_t)blockIdx.x * 256 + threadIdx.x;   // float4 index
    size_t e = v * 4;
    int c = (int)(e & 511);            // multiple of 4; never crosses 16-ch group
    int b = (int)(e >> 21);            // e / (4096*512)
    int g = c >> 4;
    float mean = stats[2 * (b * 32 + g)];
    float rstd = stats[2 * (b * 32 + g) + 1];
    float4 xv = *(const float4*)(x + e);
    float4 gv = *(const float4*)(gamma + c);
    float4 bv = *(const float4*)(beta + c);
    ushort4 o;
    o.x = f2b((xv.x - mean) * rstd * gv.x + bv.x);
    o.y = f2b((xv.y - mean) * rstd * gv.y + bv.y);
    o.z = f2b((xv.z - mean) * rstd * gv.z + bv.z);
    o.w = f2b((xv.w - mean) * rstd * gv.w + bv.w);
    *(ushort4*)(h + e) = o;
}

// ---------------------------------------------------------------------------
// 512x512 fp32 -> bf16 transposed copy (for weight matrices)
// ---------------------------------------------------------------------------
__global__ __launch_bounds__(256) void transpose_f2b(const float* __restrict__ src,
                                                     u16* __restrict__ dst) {
    __shared__ float tile[32][33];
    int tx = threadIdx.x, ty = threadIdx.y;   // (32,8)
    int r0 = blockIdx.x * 32, c0 = blockIdx.y * 32;
#pragma unroll
    for (int i = 0; i < 4; ++i)
        tile[ty + i * 8][tx] = src[(size_t)(r0 + ty + i * 8) * 512 + c0 + tx];
    __syncthreads();
#pragma unroll
    for (int i = 0; i < 4; ++i)
        dst[(size_t)(c0 + ty + i * 8) * 512 + r0 + tx] = f2b(tile[tx][ty + i * 8]);
}

// ---------------------------------------------------------------------------
// bf16 -> bf16 transposed copy (V tiles), batched via blockIdx.z
// ---------------------------------------------------------------------------
__global__ __launch_bounds__(256) void transpose_b2b(const u16* __restrict__ src,
                                                     u16* __restrict__ dst,
                                                     int src_ld, int dst_ld,
                                                     long long sSrc, long long sDst) {
    __shared__ u16 tile[32][33];
    src += (size_t)blockIdx.z * sSrc;
    dst += (size_t)blockIdx.z * sDst;
    int tx = threadIdx.x, ty = threadIdx.y;   // (32,8)
    int r0 = blockIdx.x * 32, c0 = blockIdx.y * 32;
#pragma unroll
    for (int i = 0; i < 4; ++i)
        tile[ty + i * 8][tx] = src[(size_t)(r0 + ty + i * 8) * src_ld + c0 + tx];
    __syncthreads();
#pragma unroll
    for (int i = 0; i < 4; ++i)
        dst[(size_t)(c0 + ty + i * 8) * dst_ld + r0 + tx] = tile[tx][ty + i * 8];
}

__global__ __launch_bounds__(256) void concat_bias_f(const float* __restrict__ bq,
                                                     const float* __restrict__ bk,
                                                     const float* __restrict__ bv,
                                                     float* __restrict__ dst) {
    int i = blockIdx.x * 256 + threadIdx.x;   // 1536
    const float* src = (i < 512) ? bq : (i < 1024) ? bk : bv;
    dst[i] = src[i & 511];
}

// ---------------------------------------------------------------------------
// GEMM, C = scale*(A @ B^T) + bias (+resid), bf16 operands, fp32 accum.
// global_load_lds(16B) staging. Output bf16 to C or fp32 to Cf. 128x128 tile.
// ---------------------------------------------------------------------------
__global__ __launch_bounds__(256) void gemm_bt(const u16* __restrict__ A, int lda,
                                               const u16* __restrict__ B, int ldb,
                                               u16* __restrict__ C, float* __restrict__ Cf,
                                               int ldc,
                                               const float* __restrict__ bias,
                                               const float* __restrict__ resid,
                                               int K, float scale) {
    __shared__ u16 As[128 * 32];
    __shared__ u16 Bs[128 * 32];
    const int t = threadIdx.x;
    const int lane = t & 63, w = t >> 6;
    const int wm = (w >> 1) * 64, wn = (w & 1) * 64;
    const int r = lane & 15, q = lane >> 4;
    const int m0 = blockIdx.x * 128;
    const int n0 = blockIdx.y * 128;

    floatx4 acc[4][4];
#pragma unroll
    for (int mi = 0; mi < 4; ++mi)
#pragma unroll
        for (int ni = 0; ni < 4; ++ni) acc[mi][ni] = (floatx4){0.f, 0.f, 0.f, 0.f};

    const int srow = lane >> 2;
    const int scol = (lane & 3) * 8;
    const u16* gA = A + (size_t)(m0 + w * 32 + srow) * lda + scol;
    const u16* gB = B + (size_t)(n0 + w * 32 + srow) * ldb + scol;
    u16* lA = As + w * 1024;
    u16* lB = Bs + w * 1024;

    for (int k0 = 0; k0 < K; k0 += 32) {
        __syncthreads();
        gl16(gA,                     lA);
        gl16(gA + (size_t)16 * lda,  lA + 512);
        gl16(gB,                     lB);
        gl16(gB + (size_t)16 * ldb,  lB + 512);
        gA += 32; gB += 32;
        __syncthreads();
        short8 af[4], bfr[4];
#pragma unroll
        for (int mi = 0; mi < 4; ++mi)
            af[mi] = *(const short8*)(As + (wm + mi * 16 + r) * 32 + q * 8);
#pragma unroll
        for (int ni = 0; ni < 4; ++ni)
            bfr[ni] = *(const short8*)(Bs + (wn + ni * 16 + r) * 32 + q * 8);
#pragma unroll
        for (int mi = 0; mi < 4; ++mi)
#pragma unroll
            for (int ni = 0; ni < 4; ++ni)
                acc[mi][ni] = __builtin_amdgcn_mfma_f32_16x16x32_bf16(af[mi], bfr[ni],
                                                                      acc[mi][ni], 0, 0, 0);
    }

#pragma unroll
    for (int ni = 0; ni < 4; ++ni) {
        int col = n0 + wn + ni * 16 + r;
        float bv = bias ? bias[col] : 0.f;
#pragma unroll
        for (int mi = 0; mi < 4; ++mi) {
            int rowb = m0 + wm + mi * 16 + q * 4;
#pragma unroll
            for (int i = 0; i < 4; ++i) {
                size_t off = (size_t)(rowb + i) * ldc + col;
                float v = acc[mi][ni][i] * scale + bv;
                if (resid) v += resid[off];
                if (Cf) Cf[off] = v;
                else    C[off] = f2b(v);
            }
        }
    }
}

// ---------------------------------------------------------------------------
// Fused flash attention: ao = softmax(Q K^T / sqrt(512)) V, per batch.
// Grid (64 Q-tiles, 4 batches), 256 thr. Wave w owns Q-rows qt*64+w*16..+15.
// S^T = K @ Q^T (Q frags in registers); online softmax per-lane (lane owns one
// Q-row column); P via XOR-swizzled wave-private LDS; O accum 128 f32/lane.
// Pipelined: K 32KB groups dbuf, V 32KB chunks dbuf; stages issued one full
// compute phase before the barrier that consumes them.
// ---------------------------------------------------------------------------
#define FLASH_SMEM 147456
__global__ __launch_bounds__(256, 1) void flash_k(const u16* __restrict__ qkv,
                                                  const u16* __restrict__ vt,
                                                  u16* __restrict__ ao) {
    extern __shared__ u16 smem[];
    u16* Ks = smem;                 // 2 bufs x 16384 elems (2 x 32KB): [4 sub][128 key][32 ch]
    u16* Vs = smem + 32768;         // 2 bufs x 16384 elems (2 x 32KB): [512 ch][32 key]
    u16* Pl = smem + 65536;         // 4 waves x 2048 elems (16KB): [16 row][128 key] swizzled
    const int t = threadIdx.x;
    const int lane = t & 63, w = t >> 6;
    const int r = lane & 15, q = lane >> 4;
    const int b = blockIdx.y, qt = blockIdx.x;
    const u16* qb = qkv + (size_t)b * 4096 * 1536;
    const u16* kb = qb + 512;
    const u16* vb = vt + (size_t)b * 512 * 4096;
    u16* aob = ao + (size_t)b * 4096 * 512;

    auto stageK = [&](int buf, int kt, int g) {
#pragma unroll
        for (int j = 0; j < 8; ++j) {
            int u = t + j * 256;
            int key = (u & 511) >> 2;
            int sub = u >> 9;
            int c = (u & 3) * 8;
            gl16(kb + (size_t)(kt * 128 + key) * 1536 + g * 128 + sub * 32 + c,
                 Ks + buf * 16384 + u * 8);
        }
    };
    auto stageV = [&](int buf, int kt, int k) {
#pragma unroll
        for (int j = 0; j < 8; ++j) {
            int u = t + j * 256;
            int ch = u >> 2;
            int c = (u & 3) * 8;
            gl16(vb + (size_t)ch * 4096 + kt * 128 + k * 32 + c,
                 Vs + buf * 16384 + u * 8);
        }
    };

    stageK(0, 0, 0);
    stageV(0, 0, 0);

    // Q fragments in registers: Qreg[kit] = Q[qrow][kit*32 + q*8 .. +7]
    const int qrow = qt * 64 + w * 16 + r;
    short8 Qreg[16];
#pragma unroll
    for (int kit = 0; kit < 16; ++kit)
        Qreg[kit] = *(const short8*)(qb + (size_t)qrow * 1536 + kit * 32 + q * 8);

    floatx4 acc_o[32];
#pragma unroll
    for (int ni = 0; ni < 32; ++ni) acc_o[ni] = (floatx4){0.f, 0.f, 0.f, 0.f};
    float m_run = -3.0e38f, l_run = 0.f;
    const float sc2 = 0.06375872f;   // 512^-0.5 * log2(e)
    u16* pw = Pl + w * 2048;

    for (int kt = 0; kt < 32; ++kt) {
        // ----- S^T = K_tile @ Q^T : acc_s[mi][i] = S[key=kt*128+mi*16+q*4+i][qrow]
        floatx4 acc_s[8];
#pragma unroll
        for (int mi = 0; mi < 8; ++mi) acc_s[mi] = (floatx4){0.f, 0.f, 0.f, 0.f};
#pragma unroll
        for (int g = 0; g < 4; ++g) {
            __syncthreads();                       // drains stage issued last phase
            if (g < 3) stageK((g + 1) & 1, kt, g + 1);
            const u16* kbase = Ks + (g & 1) * 16384;
#pragma unroll
            for (int s = 0; s < 4; ++s) {
                const u16* sbase = kbase + s * 4096;
#pragma unroll
                for (int mi = 0; mi < 8; ++mi) {
                    short8 af = *(const short8*)(sbase + (mi * 16 + r) * 32 + q * 8);
                    acc_s[mi] = __builtin_amdgcn_mfma_f32_16x16x32_bf16(
                        af, Qreg[g * 4 + s], acc_s[mi], 0, 0, 0);
                }
            }
        }
        // ----- online softmax (no barriers; lane owns Q-row qrow's column)
        float m_t = -3.0e38f;
#pragma unroll
        for (int mi = 0; mi < 8; ++mi)
#pragma unroll
            for (int i = 0; i < 4; ++i) m_t = fmaxf(m_t, acc_s[mi][i]);
        m_t = fmaxf(m_t, __shfl_xor(m_t, 16, 64));
        m_t = fmaxf(m_t, __shfl_xor(m_t, 32, 64));
        float m_new = fmaxf(m_run, m_t);
        unsigned long long upd = __ballot(m_t > m_run);
        float m2 = m_new * sc2;
        float p[32];
        float rs = 0.f;
#pragma unroll
        for (int mi = 0; mi < 8; ++mi)
#pragma unroll
            for (int i = 0; i < 4; ++i) {
                float pv = __builtin_amdgcn_exp2f(acc_s[mi][i] * sc2 - m2);
                p[mi * 4 + i] = pv;
                rs += pv;
            }
        rs += __shfl_xor(rs, 16, 64);
        rs += __shfl_xor(rs, 32, 64);
        if (upd) {
            float alpha = __builtin_amdgcn_exp2f((m_run - m_new) * sc2);
            l_run *= alpha;
            float a0 = __shfl(alpha, q * 4 + 0, 64);
            float a1 = __shfl(alpha, q * 4 + 1, 64);
            float a2 = __shfl(alpha, q * 4 + 2, 64);
            float a3 = __shfl(alpha, q * 4 + 3, 64);
#pragma unroll
            for (int ni = 0; ni < 32; ++ni) {
                acc_o[ni][0] *= a0; acc_o[ni][1] *= a1;
                acc_o[ni][2] *= a2; acc_o[ni][3] *= a3;
            }
        }
        l_run += rs;
        m_run = m_new;
        // ----- pack P -> bf16, write wave-private LDS [row r][128 keys], XOR swizzle
#pragma unroll
        for (int mi = 0; mi < 8; ++mi) {
            uint2 vv;
            vv.x = (unsigned)f2b(p[mi * 4 + 0]) | ((unsigned)f2b(p[mi * 4 + 1]) << 16);
            vv.y = (unsigned)f2b(p[mi * 4 + 2]) | ((unsigned)f2b(p[mi * 4 + 3]) << 16);
            *(uint2*)(pw + r * 128 + (((2 * mi + (q >> 1)) ^ (r & 7)) * 8) + (q & 1) * 4) = vv;
        }
        // ----- PV: acc_o[ni] += P[16 x 32] @ V^T[ni*16.. x 32keys]
#pragma unroll
        for (int k = 0; k < 4; ++k) {
            __syncthreads();
            if (k < 3)       stageV((k + 1) & 1, kt, k + 1);
            else if (kt < 31) stageV(0, kt + 1, 0);
            if (k == 0 && kt < 31) stageK(0, kt + 1, 0);
            short8 ap = *(const short8*)(pw + r * 128 + (((k * 4 + q) ^ (r & 7)) * 8));
            const u16* vbase = Vs + (k & 1) * 16384;
#pragma unroll
            for (int ni = 0; ni < 32; ++ni) {
                short8 bf = *(const short8*)(vbase + (ni * 16 + r) * 32 + q * 8);
                acc_o[ni] = __builtin_amdgcn_mfma_f32_16x16x32_bf16(ap, bf, acc_o[ni], 0, 0, 0);
            }
        }
    }
    // ----- epilogue: O row qbase + q*4+i, col ni*16+r; divide by l (shfl'd)
    float inv0 = 1.f / __shfl(l_run, q * 4 + 0, 64);
    float inv1 = 1.f / __shfl(l_run, q * 4 + 1, 64);
    float inv2 = 1.f / __shfl(l_run, q * 4 + 2, 64);
    float inv3 = 1.f / __shfl(l_run, q * 4 + 3, 64);
    const int rowb = qt * 64 + w * 16 + q * 4;
#pragma unroll
    for (int ni = 0; ni < 32; ++ni) {
        int col = ni * 16 + r;
        aob[(size_t)(rowb + 0) * 512 + col] = f2b(acc_o[ni][0] * inv0);
        aob[(size_t)(rowb + 1) * 512 + col] = f2b(acc_o[ni][1] * inv1);
        aob[(size_t)(rowb + 2) * 512 + col] = f2b(acc_o[ni][2] * inv2);
        aob[(size_t)(rowb + 3) * 512 + col] = f2b(acc_o[ni][3] * inv3);
    }
}

// ---------------------------------------------------------------------------
extern "C" void kernel_launch(void* const* d_in, const int* in_sizes, int n_in,
                              void* d_out, int out_size, void* d_ws, size_t ws_size,
                              hipStream_t stream) {
    const float* x     = (const float*)d_in[0];
    const float* gamma = (const float*)d_in[1];
    const float* beta  = (const float*)d_in[2];
    const float* Wq    = (const float*)d_in[3];
    const float* bq    = (const float*)d_in[4];
    const float* Wk    = (const float*)d_in[5];
    const float* bk    = (const float*)d_in[6];
    const float* Wv    = (const float*)d_in[7];
    const float* bv    = (const float*)d_in[8];
    const float* Wo    = (const float*)d_in[9];
    const float* bo    = (const float*)d_in[10];
    float* out = (float*)d_out;

    // B=4, N=4096, C=512, G=32 — ws layout (no S needed anymore)
    char* ws = (char*)d_ws;
    float* stats  = (float*)(ws);                        // 128*2 f32
    float* bqkv   = (float*)(ws + 4096);                 // 1536 f32
    u16*   wqkv_t = (u16*)(ws + 16384);                  // [1536,512]
    u16*   wo_t   = wqkv_t + (size_t)1536 * 512;
    u16*   h      = wo_t + (size_t)512 * 512;            // [16384,512] (aliased as ao)
    u16*   qkv    = h   + (size_t)16384 * 512;           // [16384,1536]
    u16*   vt     = qkv + (size_t)16384 * 1536;          // [4][512][4096]
    u16*   ao     = h;                                   // h dead after QKV GEMM

    const long long sQKV = (long long)4096 * 1536;
    const long long sVT  = (long long)512 * 4096;

    dim3 tblk(32, 8, 1);
    transpose_f2b<<<dim3(16, 16, 1), tblk, 0, stream>>>(Wq, wqkv_t);
    transpose_f2b<<<dim3(16, 16, 1), tblk, 0, stream>>>(Wk, wqkv_t + 512 * 512);
    transpose_f2b<<<dim3(16, 16, 1), tblk, 0, stream>>>(Wv, wqkv_t + 1024 * 512);
    transpose_f2b<<<dim3(16, 16, 1), tblk, 0, stream>>>(Wo, wo_t);
    concat_bias_f<<<6, 256, 0, stream>>>(bq, bk, bv, bqkv);

    gn_stats_k<<<128, 256, 0, stream>>>(x, stats);
    gn_apply_k<<<8192, 256, 0, stream>>>(x, gamma, beta, stats, h);

    // QKV: [16384,512] @ [512,1536] -> qkv (+bias)
    gemm_bt<<<dim3(128, 12, 1), 256, 0, stream>>>(h, 512, wqkv_t, 512,
                                                  qkv, nullptr, 1536, bqkv, nullptr,
                                                  512, 1.0f);
    // v -> vt[b][c][n]
    transpose_b2b<<<dim3(128, 16, 4), tblk, 0, stream>>>(qkv + 1024, vt, 1536, 4096,
                                                         sQKV, sVT);
    // fused attention -> ao
    hipFuncSetAttribute((const void*)flash_k,
                        hipFuncAttributeMaxDynamicSharedMemorySize, FLASH_SMEM);
    flash_k<<<dim3(64, 4, 1), 256, FLASH_SMEM, stream>>>(qkv, vt, ao);

    // out = ao @ Wo + bo + x   (fp32 output + bias + residual)
    gemm_bt<<<dim3(128, 4, 1), 256, 0, stream>>>(ao, 512, wo_t, 512,
                                                 nullptr, out, 512, bo, x,
                                                 512, 1.0f);
}